// Round 12
// baseline (66.385 us; speedup 1.0000x reference)
//
#include <hip/hip_runtime.h>
#include <hip/hip_bf16.h>

// DLRM forward, bf16-MFMA, 6 dispatches with co-dispatched independent work.
// d1 mix: [gather+dots+Tg | wconv x5 | gemm0(self-conv bw0)]   (2064 blocks)
// d2 gemm1, d3 botmix (bot + bot-pairs), d4 top0, d5 top1, d6 top2+out.
// B=2048, dense 13, emb 26x100000x64, 27 feats -> 351 pairs,
// top MLP 415(->512 pad)->1024->512->256->1 sigmoid.

#define BATCH 2048
#define VOCAB 100000
#define NSPARSE 26
#define NFEA 27
#define NPAIR 351
#define RLD 512

typedef __attribute__((ext_vector_type(8))) __bf16 bf16x8;
typedef __attribute__((ext_vector_type(4))) float f32x4;
typedef __hip_bfloat16 bf16;

#define GLOAD16(g, l)                                                          \
    __builtin_amdgcn_global_load_lds(                                          \
        (const __attribute__((address_space(1))) unsigned int*)(g),            \
        (__attribute__((address_space(3))) unsigned int*)(l), 16, 0, 0)

template<int BK>
__device__ __forceinline__ int swz(int row, int s) {
    return (BK == 128) ? (s ^ (row & 15))
         : (BK == 64)  ? (s ^ (row & 7))
                       : (s ^ ((row >> 1) & 3));
}

// ---------------------------------------------------------------------------
// mix1: three independent roles in one dispatch.
//   blocks [0,512):      gather 4 rows -> T(LDS f32) -> 325 dots -> R[64+p],
//                        Tg (bf16 emb copy), zero-pad R[415:512)
//   blocks [512,1808):   wconv (bw1,bw2,tw0,tw1,tw2 transpose+bf16)
//   blocks [1808,2064):  gemm0: h0 = relu(dense @ bw0 + bb0), self-converts
// ---------------------------------------------------------------------------
struct Mix1Args {
    const int* cat; const float* tables; bf16* R; bf16* Tg;
    const float* wsrc[5]; bf16* wdst[5];
    int wK[5], wN[5], wKp[5], wt0[6];
    const float* dense; const float* bw0; const float* bb0; bf16* h0;
};

__device__ void gather_role(const Mix1Args& a, char* ldsc, int gb)
{
    float (*T)[NFEA][65] = (float(*)[NFEA][65])ldsc;   // 28080 B
    const int t  = threadIdx.x;
    const int b0 = gb * 4;

    for (int l = t; l < 4 * NSPARSE * 16; l += 256) {
        const int r = l / (NSPARSE * 16), rem = l % (NSPARSE * 16);
        const int j = rem >> 4, c = (rem & 15) * 4;
        const int idx = a.cat[(b0 + r) * NSPARSE + j];
        const float4 v =
            *(const float4*)&a.tables[((size_t)j * VOCAB + idx) * 64 + c];
        float* dst = &T[r][j + 1][c];
        dst[0] = v.x; dst[1] = v.y; dst[2] = v.z; dst[3] = v.w;
    }
    for (int z = t; z < 4 * (RLD - 415); z += 256) {
        const int r = z / (RLD - 415), c = z % (RLD - 415);
        a.R[(size_t)(b0 + r) * RLD + 415 + c] = __float2bfloat16(0.f);
    }
    __syncthreads();

    // Tg: bf16 copy of gathered embeddings for botmix
    for (int l = t; l < 4 * NSPARSE * 8; l += 256) {
        const int r = l / (NSPARSE * 8), rem = l % (NSPARSE * 8);
        const int j = rem >> 3, k8 = rem & 7;
        union { bf16 h[8]; bf16x8 v; } pk;
#pragma unroll
        for (int u = 0; u < 8; ++u)
            pk.h[u] = __float2bfloat16(T[r][j + 1][k8 * 8 + u]);
        *(bf16x8*)&a.Tg[((size_t)(b0 + r) * NSPARSE + j) * 64 + k8 * 8] = pk.v;
    }

    // 325 non-bot pairs (j >= 1), f32 as before
    for (int task = t; task < 4 * NPAIR; task += 256) {
        const int r = task / NPAIR, p = task % NPAIR;
        int i = (int)((1.0f + sqrtf(1.0f + 8.0f * (float)p)) * 0.5f);
        while (i * (i - 1) / 2 > p) --i;
        while ((i + 1) * i / 2 <= p) ++i;
        const int j = p - i * (i - 1) / 2;
        if (j == 0) continue;                    // bot pairs done in botmix
        float s = 0.f;
#pragma unroll 16
        for (int k = 0; k < 64; ++k) s += T[r][i][k] * T[r][j][k];
        a.R[(size_t)(b0 + r) * RLD + 64 + p] = __float2bfloat16(s);
    }
}

__device__ void wconv_role(const Mix1Args& a, char* ldsc, int wb)
{
    float (*Ts)[33] = (float(*)[33])ldsc;
    int w = 0;
    while (w < 4 && wb >= a.wt0[w + 1]) ++w;
    const int rel = wb - a.wt0[w];
    const int K = a.wK[w], N = a.wN[w], Kp = a.wKp[w];
    const int nbn = N >> 5;
    const int tk = rel / nbn, tn = rel % nbn;
    const int tx = threadIdx.x & 31, ty = threadIdx.x >> 5;

    const float* src = a.wsrc[w];
    bf16* dst = a.wdst[w];
#pragma unroll
    for (int rr = 0; rr < 4; ++rr) {
        const int k = tk * 32 + ty + rr * 8, n = tn * 32 + tx;
        Ts[ty + rr * 8][tx] = (k < K) ? src[(size_t)k * N + n] : 0.f;
    }
    __syncthreads();
#pragma unroll
    for (int rr = 0; rr < 4; ++rr) {
        const int n = tn * 32 + ty + rr * 8, kp = tk * 32 + tx;
        dst[(size_t)n * Kp + kp] = __float2bfloat16(Ts[tx][ty + rr * 8]);
    }
}

__device__ void gemm0_role(const Mix1Args& a, char* ldsc, int mb)
{
    bf16* As = (bf16*)ldsc;            // 64x32 = 4096 B
    bf16* Bs = (bf16*)(ldsc + 4096);   // 64x32 = 4096 B
    constexpr int N = 512;

    const int t = threadIdx.x;
    const int nbn = N >> 6;            // 8
    const int bm = mb / nbn, bn = mb % nbn;
    const int row0 = bm << 6, n0 = bn << 6;
    const int wid = t >> 6, lane = t & 63;
    const int wr = wid >> 1, wc = wid & 1;
    const int lr = lane & 15, q = lane >> 4;

    for (int idx = t; idx < 64 * 32; idx += 256) {
        const int r = idx >> 5, c = idx & 31;
        const float v = (c < 13) ? a.dense[(size_t)(row0 + r) * 13 + c] : 0.f;
        As[r * 32 + swz<32>(r, c >> 3) * 8 + (c & 7)] = __float2bfloat16(v);
    }
    for (int idx = t; idx < 64 * 32; idx += 256) {
        const int r = idx >> 5, c = idx & 31;   // r = n-row, c = k
        const float v = (c < 13) ? a.bw0[(size_t)c * N + n0 + r] : 0.f;
        Bs[r * 32 + swz<32>(r, c >> 3) * 8 + (c & 7)] = __float2bfloat16(v);
    }
    __syncthreads();

    f32x4 acc[2][2] = {};
    bf16x8 af[2], bfr[2];
#pragma unroll
    for (int m = 0; m < 2; ++m) {
        const int r = wr * 32 + 16 * m + lr;
        af[m] = *(const bf16x8*)((const char*)As + r * 64 + swz<32>(r, q) * 16);
    }
#pragma unroll
    for (int n = 0; n < 2; ++n) {
        const int r = wc * 32 + 16 * n + lr;
        bfr[n] = *(const bf16x8*)((const char*)Bs + r * 64 + swz<32>(r, q) * 16);
    }
#pragma unroll
    for (int m = 0; m < 2; ++m)
#pragma unroll
        for (int n = 0; n < 2; ++n)
            acc[m][n] = __builtin_amdgcn_mfma_f32_16x16x32_bf16(
                af[m], bfr[n], acc[m][n], 0, 0, 0);

#pragma unroll
    for (int n = 0; n < 2; ++n) {
        const int col = n0 + wc * 32 + 16 * n + lr;
        const float bv = a.bb0[col];
#pragma unroll
        for (int m = 0; m < 2; ++m) {
#pragma unroll
            for (int i = 0; i < 4; ++i) {
                const int row = row0 + wr * 32 + 16 * m + q * 4 + i;
                a.h0[(size_t)row * 512 + col] =
                    __float2bfloat16(fmaxf(acc[m][n][i] + bv, 0.f));
            }
        }
    }
}

__global__ __launch_bounds__(256) void mix1_kernel(Mix1Args a)
{
    __shared__ __align__(16) char lds[28288];
    const int bid = blockIdx.x;
    if (bid < 512)            gather_role(a, lds, bid);
    else if (bid < 1808)      wconv_role(a, lds, bid - 512);
    else                      gemm0_role(a, lds, bid - 1808);
}

// ---------------------------------------------------------------------------
// botmix: bot = relu(h1 @ bw2t + bb2) -> R[:, :64] + 26 bot-pairs from Tg.
// 8 rows/block, 256 blocks.
// ---------------------------------------------------------------------------
__global__ __launch_bounds__(256) void botmix_kernel(
    const bf16* __restrict__ h1, const bf16* __restrict__ bw2t,
    const float* __restrict__ bb2, const bf16* __restrict__ Tg,
    bf16* __restrict__ R)
{
    __shared__ bf16  h1s[8][256];
    __shared__ float bots[8][64];
    const int t  = threadIdx.x;
    const int b0 = blockIdx.x * 8;

    {   const int r = t >> 5, c = (t & 31) * 8;
        *(bf16x8*)&h1s[r][c] = *(const bf16x8*)&h1[(size_t)(b0 + r) * 256 + c]; }
    __syncthreads();

    for (int o = t; o < 512; o += 256) {
        const int r = o >> 6, n = o & 63;
        float s = bb2[n];
        const bf16* wrow = bw2t + (size_t)n * 256;
#pragma unroll 8
        for (int k = 0; k < 256; k += 8) {
            const bf16x8 hv = *(const bf16x8*)&h1s[r][k];
            const bf16x8 wv = *(const bf16x8*)&wrow[k];
#pragma unroll
            for (int u = 0; u < 8; ++u)
                s += (float)hv[u] * (float)wv[u];
        }
        s = fmaxf(s, 0.f);
        bots[r][n] = s;
        R[(size_t)(b0 + r) * RLD + n] = __float2bfloat16(s);
    }
    __syncthreads();

    if (t < 8 * NSPARSE) {
        const int r = t / NSPARSE, iz = t % NSPARSE, i = iz + 1;
        const bf16* tgrow = Tg + ((size_t)(b0 + r) * NSPARSE + iz) * 64;
        float s = 0.f;
#pragma unroll
        for (int k8 = 0; k8 < 8; ++k8) {
            const bf16x8 ev = *(const bf16x8*)&tgrow[k8 * 8];
#pragma unroll
            for (int u = 0; u < 8; ++u)
                s += (float)ev[u] * bots[r][k8 * 8 + u];
        }
        R[(size_t)(b0 + r) * RLD + 64 + i * (i - 1) / 2] = __float2bfloat16(s);
    }
}

// ---------------------------------------------------------------------------
// bf16 MFMA GEMM (R11-proven): C = relu(A @ Wt^T + bias). Single-buffered.
// ---------------------------------------------------------------------------
template<int BK, int WR, int WC, int MREP, int NREP>
__global__ __launch_bounds__(256) void gemm_bf16(
    const bf16* __restrict__ A, const bf16* __restrict__ Wt,
    const float* __restrict__ bias, bf16* __restrict__ C,
    int M, int N, int K, int ldC)
{
    constexpr int BM    = WR * MREP * 16;
    constexpr int BN    = WC * NREP * 16;
    constexpr int ROWB  = BK * 2;
    constexpr int SLOTS = BK / 8;
    constexpr int KKS   = BK / 32;
    constexpr int PA    = BM * SLOTS / 256;
    constexpr int PB    = BN * SLOTS / 256;

    __shared__ __align__(16) bf16 As[BM * BK];
    __shared__ __align__(16) bf16 Bs[BN * BK];

    const int t   = threadIdx.x;
    const int nbn = N / BN;
    const int bm  = blockIdx.x / nbn;
    const int bn  = blockIdx.x % nbn;
    const int row0 = bm * BM, n0 = bn * BN;

    const int wid  = t >> 6, lane = t & 63;
    const int wr   = wid / WC, wc = wid % WC;
    const int lr   = lane & 15;
    const int q    = lane >> 4;
    const int sslot = t % SLOTS;

    const bf16* Ab[PA];
    const bf16* Bb[PB];
#pragma unroll
    for (int p = 0; p < PA; ++p) {
        const int r = (p * 256 + t) / SLOTS;
        Ab[p] = A + (size_t)(row0 + r) * K + swz<BK>(r, sslot) * 8;
    }
#pragma unroll
    for (int p = 0; p < PB; ++p) {
        const int r = (p * 256 + t) / SLOTS;
        Bb[p] = Wt + (size_t)(n0 + r) * K + swz<BK>(r, sslot) * 8;
    }

    f32x4 acc[MREP][NREP] = {};

    for (int k0 = 0; k0 < K; k0 += BK) {
#pragma unroll
        for (int p = 0; p < PA; ++p)
            GLOAD16(Ab[p] + k0, (char*)As + (p * 256 + t) * 16);
#pragma unroll
        for (int p = 0; p < PB; ++p)
            GLOAD16(Bb[p] + k0, (char*)Bs + (p * 256 + t) * 16);
        __syncthreads();

        bf16x8 af[KKS][MREP], bfr[KKS][NREP];
#pragma unroll
        for (int kk = 0; kk < KKS; ++kk) {
#pragma unroll
            for (int m = 0; m < MREP; ++m) {
                const int r = wr * MREP * 16 + 16 * m + lr;
                af[kk][m] = *(const bf16x8*)((const char*)As + r * ROWB +
                                             swz<BK>(r, kk * 4 + q) * 16);
            }
#pragma unroll
            for (int n = 0; n < NREP; ++n) {
                const int r = wc * NREP * 16 + 16 * n + lr;
                bfr[kk][n] = *(const bf16x8*)((const char*)Bs + r * ROWB +
                                              swz<BK>(r, kk * 4 + q) * 16);
            }
        }
#pragma unroll
        for (int kk = 0; kk < KKS; ++kk)
#pragma unroll
            for (int m = 0; m < MREP; ++m)
#pragma unroll
                for (int n = 0; n < NREP; ++n)
                    acc[m][n] = __builtin_amdgcn_mfma_f32_16x16x32_bf16(
                        af[kk][m], bfr[kk][n], acc[m][n], 0, 0, 0);
        __syncthreads();
    }

    // D layout: col = lane&15, row = (lane>>4)*4 + i
#pragma unroll
    for (int n = 0; n < NREP; ++n) {
        const int col = n0 + wc * NREP * 16 + 16 * n + lr;
        const float bv = bias[col];
#pragma unroll
        for (int m = 0; m < MREP; ++m) {
#pragma unroll
            for (int i = 0; i < 4; ++i) {
                const int row = row0 + wr * MREP * 16 + 16 * m + q * 4 + i;
                C[(size_t)row * ldC + col] =
                    __float2bfloat16(fmaxf(acc[m][n][i] + bv, 0.f));
            }
        }
    }
}

// ---------------------------------------------------------------------------
// top2 + top3 fused (R11-proven): 32 rows x all 256 cols + sigmoid dot.
// ---------------------------------------------------------------------------
__global__ __launch_bounds__(256) void top2_kernel(
    const bf16* __restrict__ A, const bf16* __restrict__ Wt,
    const float* __restrict__ bias, const float* __restrict__ w3,
    const float* __restrict__ b3, float* __restrict__ out)
{
    constexpr int BK = 64, BM = 32, K = 512;
    constexpr int SLOTS = 8, KKS = 2, PA = 1, PB = 8;

    __shared__ __align__(16) bf16 As[BM * BK];
    __shared__ __align__(16) bf16 Bs[256 * BK];
    __shared__ float rsum[BM];

    const int t = threadIdx.x;
    const int row0 = blockIdx.x * BM;
    const int wc = t >> 6, lane = t & 63;
    const int lr = lane & 15, q = lane >> 4;
    const int sslot = t % SLOTS;

    const bf16* Ab[PA];
    const bf16* Bb[PB];
#pragma unroll
    for (int p = 0; p < PA; ++p) {
        const int r = (p * 256 + t) / SLOTS;
        Ab[p] = A + (size_t)(row0 + r) * K + swz<BK>(r, sslot) * 8;
    }
#pragma unroll
    for (int p = 0; p < PB; ++p) {
        const int r = (p * 256 + t) / SLOTS;
        Bb[p] = Wt + (size_t)r * K + swz<BK>(r, sslot) * 8;
    }

    f32x4 acc[2][4] = {};

    for (int k0 = 0; k0 < K; k0 += BK) {
#pragma unroll
        for (int p = 0; p < PA; ++p)
            GLOAD16(Ab[p] + k0, (char*)As + (p * 256 + t) * 16);
#pragma unroll
        for (int p = 0; p < PB; ++p)
            GLOAD16(Bb[p] + k0, (char*)Bs + (p * 256 + t) * 16);
        __syncthreads();

        bf16x8 af[KKS][2], bfr[KKS][4];
#pragma unroll
        for (int kk = 0; kk < KKS; ++kk) {
#pragma unroll
            for (int m = 0; m < 2; ++m) {
                const int r = 16 * m + lr;
                af[kk][m] = *(const bf16x8*)((const char*)As + r * 128 +
                                             swz<BK>(r, kk * 4 + q) * 16);
            }
#pragma unroll
            for (int n = 0; n < 4; ++n) {
                const int r = wc * 64 + 16 * n + lr;
                bfr[kk][n] = *(const bf16x8*)((const char*)Bs + r * 128 +
                                              swz<BK>(r, kk * 4 + q) * 16);
            }
        }
#pragma unroll
        for (int kk = 0; kk < KKS; ++kk)
#pragma unroll
            for (int m = 0; m < 2; ++m)
#pragma unroll
                for (int n = 0; n < 4; ++n)
                    acc[m][n] = __builtin_amdgcn_mfma_f32_16x16x32_bf16(
                        af[kk][m], bfr[kk][n], acc[m][n], 0, 0, 0);
        __syncthreads();
    }

    if (t < BM) rsum[t] = 0.f;
    __syncthreads();

#pragma unroll
    for (int m = 0; m < 2; ++m) {
#pragma unroll
        for (int i = 0; i < 4; ++i) {
            float val = 0.f;
#pragma unroll
            for (int n = 0; n < 4; ++n) {
                const int col = wc * 64 + 16 * n + lr;
                val += fmaxf(acc[m][n][i] + bias[col], 0.f) * w3[col];
            }
            val += __shfl_xor(val, 1);
            val += __shfl_xor(val, 2);
            val += __shfl_xor(val, 4);
            val += __shfl_xor(val, 8);
            if (lr == 0) atomicAdd(&rsum[16 * m + q * 4 + i], val);
        }
    }
    __syncthreads();
    if (t < BM)
        out[row0 + t] = 1.f / (1.f + expf(-(rsum[t] + b3[0])));
}

// ---------------------------------------------------------------------------
extern "C" void kernel_launch(void* const* d_in, const int* in_sizes, int n_in,
                              void* d_out, int out_size, void* d_ws, size_t ws_size,
                              hipStream_t stream)
{
    const float* dense   = (const float*)d_in[0];
    const int*   cat_idx = (const int*)  d_in[1];
    const float* tables  = (const float*)d_in[2];
    const float* bw0 = (const float*)d_in[3];
    const float* bb0 = (const float*)d_in[4];
    const float* bw1 = (const float*)d_in[5];
    const float* bb1 = (const float*)d_in[6];
    const float* bw2 = (const float*)d_in[7];
    const float* bb2 = (const float*)d_in[8];
    const float* tw0 = (const float*)d_in[9];
    const float* tb0 = (const float*)d_in[10];
    const float* tw1 = (const float*)d_in[11];
    const float* tb1 = (const float*)d_in[12];
    const float* tw2 = (const float*)d_in[13];
    const float* tb2 = (const float*)d_in[14];
    const float* tw3 = (const float*)d_in[15];
    const float* tb3 = (const float*)d_in[16];

    bf16* p = (bf16*)d_ws;
    bf16* h0   = p; p += (size_t)BATCH * 512;
    bf16* h1   = p; p += (size_t)BATCH * 256;
    bf16* R    = p; p += (size_t)BATCH * RLD;
    bf16* r0   = p; p += (size_t)BATCH * 1024;
    bf16* r1   = p; p += (size_t)BATCH * 512;
    bf16* Tg   = p; p += (size_t)BATCH * NSPARSE * 64;
    bf16* bw1t = p; p += 256 * 512;
    bf16* bw2t = p; p += 64 * 256;
    bf16* tw0t = p; p += 1024 * RLD;
    bf16* tw1t = p; p += 512 * 1024;
    bf16* tw2t = p; p += 256 * 512;
    float* out = (float*)d_out;

    Mix1Args ma;
    ma.cat = cat_idx; ma.tables = tables; ma.R = R; ma.Tg = Tg;
    ma.wsrc[0] = bw1; ma.wdst[0] = bw1t; ma.wK[0] = 512;  ma.wN[0] = 256;  ma.wKp[0] = 512;
    ma.wsrc[1] = bw2; ma.wdst[1] = bw2t; ma.wK[1] = 256;  ma.wN[1] = 64;   ma.wKp[1] = 256;
    ma.wsrc[2] = tw0; ma.wdst[2] = tw0t; ma.wK[2] = 415;  ma.wN[2] = 1024; ma.wKp[2] = RLD;
    ma.wsrc[3] = tw1; ma.wdst[3] = tw1t; ma.wK[3] = 1024; ma.wN[3] = 512;  ma.wKp[3] = 1024;
    ma.wsrc[4] = tw2; ma.wdst[4] = tw2t; ma.wK[4] = 512;  ma.wN[4] = 256;  ma.wKp[4] = 512;
    int tiles = 0;
    for (int w = 0; w < 5; ++w) {
        ma.wt0[w] = tiles;
        tiles += (ma.wKp[w] >> 5) * (ma.wN[w] >> 5);
    }
    ma.wt0[5] = tiles;   // 1296
    ma.dense = dense; ma.bw0 = bw0; ma.bb0 = bb0; ma.h0 = h0;

    // d1: gather(512) | wconv(1296) | gemm0(256)
    mix1_kernel<<<512 + tiles + 256, 256, 0, stream>>>(ma);

    // d2: h1 = relu(h0 @ bw1^T + bb1)
    gemm_bf16<128, 2, 2, 2, 2><<<(BATCH / 64) * (256 / 64), 256, 0, stream>>>(
        h0, bw1t, bb1, h1, BATCH, 256, 512, 256);

    // d3: bot + bot-pairs -> R
    botmix_kernel<<<BATCH / 8, 256, 0, stream>>>(h1, bw2t, bb2, Tg, R);

    // d4: r0 = relu(R @ tw0^T + tb0)
    gemm_bf16<128, 2, 2, 2, 2><<<(BATCH / 64) * (1024 / 64), 256, 0, stream>>>(
        R, tw0t, tb0, r0, BATCH, 1024, RLD, 1024);

    // d5: r1 = relu(r0 @ tw1^T + tb1)
    gemm_bf16<128, 2, 2, 2, 2><<<(BATCH / 64) * (512 / 64), 256, 0, stream>>>(
        r0, tw1t, tb1, r1, BATCH, 512, 1024, 512);

    // d6: out = sigmoid(relu(r1 @ tw2^T + tb2) . tw3 + tb3)
    top2_kernel<<<BATCH / 32, 256, 0, stream>>>(r1, tw2t, tb2, tw3, tb3, out);
}

// Round 13
// 59.703 us; speedup vs baseline: 1.1119x; 1.1119x over previous
//
#include <hip/hip_runtime.h>
#include <hip/hip_bf16.h>

// DLRM forward, bf16-MFMA, BK=128 GEMMs, 8 dispatches.
// R13 = R11 with BM=32 tiles for the underfilled GEMMs (gemm1/gemm2/top1).
// B=2048, dense 13, emb 26x100000x64, 27 feats -> 351 pairs,
// top MLP 415(->512 pad)->1024->512->256->1 sigmoid.

#define BATCH 2048
#define VOCAB 100000
#define NSPARSE 26
#define NFEA 27
#define NPAIR 351
#define RLD 512            // padded R row stride (415 -> 512, %128==0)

typedef __attribute__((ext_vector_type(8))) __bf16 bf16x8;
typedef __attribute__((ext_vector_type(4))) float f32x4;
typedef __hip_bfloat16 bf16;

#define GLOAD16(g, l)                                                          \
    __builtin_amdgcn_global_load_lds(                                          \
        (const __attribute__((address_space(1))) unsigned int*)(g),            \
        (__attribute__((address_space(3))) unsigned int*)(l), 16, 0, 0)

template<int BK>
__device__ __forceinline__ int swz(int row, int s) {
    return (BK == 128) ? (s ^ (row & 15))
         : (BK == 64)  ? (s ^ (row & 7))
                       : (s ^ ((row >> 1) & 3));
}

// ---------------------------------------------------------------------------
// bf16 MFMA GEMM: C[M,ldC] = relu(A[M,K] @ Wt[N,K]^T + bias), bf16 I/O,
// f32 accum. 4 waves (WR x WC), wave sub-tile (MREP*16) x (NREP*16).
// Single-buffered LDS, 16B-slot swizzle both sides (BK=128: s^=row&15).
// DENSEPAD: A raw f32 [M][13] staged+padded to K=32 on VALU.
// ---------------------------------------------------------------------------
template<int BK, int WR, int WC, int MREP, int NREP, bool DENSEPAD>
__global__ __launch_bounds__(256) void gemm_bf16(
    const void* __restrict__ Araw,  // bf16 [M][K]  (or f32 [M][13])
    const bf16* __restrict__ Wt,    // [N][K] = W^T
    const float* __restrict__ bias,
    bf16* __restrict__ C,           // [M][ldC]
    int M, int N, int K, int ldC)
{
    constexpr int BM    = WR * MREP * 16;
    constexpr int BN    = WC * NREP * 16;
    constexpr int ROWB  = BK * 2;
    constexpr int SLOTS = BK / 8;
    constexpr int KKS   = BK / 32;
    constexpr int PA    = BM * SLOTS / 256;
    constexpr int PB    = BN * SLOTS / 256;

    __shared__ __align__(16) bf16 As[BM * BK];
    __shared__ __align__(16) bf16 Bs[BN * BK];

    const int t   = threadIdx.x;
    const int nbn = N / BN;
    const int bm  = blockIdx.x / nbn;
    const int bn  = blockIdx.x % nbn;
    const int row0 = bm * BM, n0 = bn * BN;

    const int wid  = t >> 6, lane = t & 63;
    const int wr   = wid / WC, wc = wid % WC;
    const int lr   = lane & 15;
    const int q    = lane >> 4;
    const int sslot = t % SLOTS;

    const bf16* Ab[PA];
    const bf16* Bb[PB];
#pragma unroll
    for (int p = 0; p < PA; ++p) {
        const int r = (p * 256 + t) / SLOTS;
        if (!DENSEPAD)
            Ab[p] = (const bf16*)Araw + (size_t)(row0 + r) * K +
                    swz<BK>(r, sslot) * 8;
    }
#pragma unroll
    for (int p = 0; p < PB; ++p) {
        const int r = (p * 256 + t) / SLOTS;
        Bb[p] = Wt + (size_t)(n0 + r) * K + swz<BK>(r, sslot) * 8;
    }

    f32x4 acc[MREP][NREP] = {};

    for (int k0 = 0; k0 < K; k0 += BK) {
        if constexpr (DENSEPAD) {
            const float* Df = (const float*)Araw;
#pragma unroll
            for (int idx = t; idx < BM * 32; idx += 256) {
                const int r = idx >> 5, c = idx & 31;
                const float v = (c < 13) ? Df[(size_t)(row0 + r) * 13 + c] : 0.f;
                As[r * 32 + swz<32>(r, c >> 3) * 8 + (c & 7)] =
                    __float2bfloat16(v);
            }
        } else {
#pragma unroll
            for (int p = 0; p < PA; ++p)
                GLOAD16(Ab[p] + k0, (char*)As + (p * 256 + t) * 16);
        }
#pragma unroll
        for (int p = 0; p < PB; ++p)
            GLOAD16(Bb[p] + k0, (char*)Bs + (p * 256 + t) * 16);
        __syncthreads();

        bf16x8 af[KKS][MREP], bfr[KKS][NREP];
#pragma unroll
        for (int kk = 0; kk < KKS; ++kk) {
#pragma unroll
            for (int m = 0; m < MREP; ++m) {
                const int r = wr * MREP * 16 + 16 * m + lr;
                af[kk][m] = *(const bf16x8*)((const char*)As + r * ROWB +
                                             swz<BK>(r, kk * 4 + q) * 16);
            }
#pragma unroll
            for (int n = 0; n < NREP; ++n) {
                const int r = wc * NREP * 16 + 16 * n + lr;
                bfr[kk][n] = *(const bf16x8*)((const char*)Bs + r * ROWB +
                                              swz<BK>(r, kk * 4 + q) * 16);
            }
        }
#pragma unroll
        for (int kk = 0; kk < KKS; ++kk)
#pragma unroll
            for (int m = 0; m < MREP; ++m)
#pragma unroll
                for (int n = 0; n < NREP; ++n)
                    acc[m][n] = __builtin_amdgcn_mfma_f32_16x16x32_bf16(
                        af[kk][m], bfr[kk][n], acc[m][n], 0, 0, 0);
        __syncthreads();
    }

    // D layout: col = lane&15, row = (lane>>4)*4 + i
#pragma unroll
    for (int n = 0; n < NREP; ++n) {
        const int col = n0 + wc * NREP * 16 + 16 * n + lr;
        const float bv = bias[col];
#pragma unroll
        for (int m = 0; m < MREP; ++m) {
#pragma unroll
            for (int i = 0; i < 4; ++i) {
                const int row = row0 + wr * MREP * 16 + 16 * m + q * 4 + i;
                float v = fmaxf(acc[m][n][i] + bv, 0.f);
                C[(size_t)row * ldC + col] = __float2bfloat16(v);
            }
        }
    }
}

// ---------------------------------------------------------------------------
// top2 + top3 fused: each block computes 32 rows x ALL 256 cols of
// relu(r1 @ tw2^T + tb2), then out[row] = sigmoid(dot(., tw3) + tb3).
// BK=64, 4 waves N-split (each 32x64), LDS rsum reduce. Grid = 64 blocks.
// ---------------------------------------------------------------------------
__global__ __launch_bounds__(256) void top2_kernel(
    const bf16* __restrict__ A,      // r1 [B][512]
    const bf16* __restrict__ Wt,     // tw2t [256][512]
    const float* __restrict__ bias,  // tb2
    const float* __restrict__ w3,    // tw3 [256]
    const float* __restrict__ b3,    // tb3
    float* __restrict__ out)
{
    constexpr int BK = 64, BM = 32, K = 512;
    constexpr int SLOTS = 8, KKS = 2, PA = 1, PB = 8;

    __shared__ __align__(16) bf16 As[BM * BK];
    __shared__ __align__(16) bf16 Bs[256 * BK];
    __shared__ float rsum[BM];

    const int t = threadIdx.x;
    const int row0 = blockIdx.x * BM;
    const int wc = t >> 6, lane = t & 63;
    const int lr = lane & 15, q = lane >> 4;
    const int sslot = t % SLOTS;

    const bf16* Ab[PA];
    const bf16* Bb[PB];
#pragma unroll
    for (int p = 0; p < PA; ++p) {
        const int r = (p * 256 + t) / SLOTS;
        Ab[p] = A + (size_t)(row0 + r) * K + swz<BK>(r, sslot) * 8;
    }
#pragma unroll
    for (int p = 0; p < PB; ++p) {
        const int r = (p * 256 + t) / SLOTS;
        Bb[p] = Wt + (size_t)r * K + swz<BK>(r, sslot) * 8;
    }

    f32x4 acc[2][4] = {};

    for (int k0 = 0; k0 < K; k0 += BK) {
#pragma unroll
        for (int p = 0; p < PA; ++p)
            GLOAD16(Ab[p] + k0, (char*)As + (p * 256 + t) * 16);
#pragma unroll
        for (int p = 0; p < PB; ++p)
            GLOAD16(Bb[p] + k0, (char*)Bs + (p * 256 + t) * 16);
        __syncthreads();

        bf16x8 af[KKS][2], bfr[KKS][4];
#pragma unroll
        for (int kk = 0; kk < KKS; ++kk) {
#pragma unroll
            for (int m = 0; m < 2; ++m) {
                const int r = 16 * m + lr;
                af[kk][m] = *(const bf16x8*)((const char*)As + r * 128 +
                                             swz<BK>(r, kk * 4 + q) * 16);
            }
#pragma unroll
            for (int n = 0; n < 4; ++n) {
                const int r = wc * 64 + 16 * n + lr;
                bfr[kk][n] = *(const bf16x8*)((const char*)Bs + r * 128 +
                                              swz<BK>(r, kk * 4 + q) * 16);
            }
        }
#pragma unroll
        for (int kk = 0; kk < KKS; ++kk)
#pragma unroll
            for (int m = 0; m < 2; ++m)
#pragma unroll
                for (int n = 0; n < 4; ++n)
                    acc[m][n] = __builtin_amdgcn_mfma_f32_16x16x32_bf16(
                        af[kk][m], bfr[kk][n], acc[m][n], 0, 0, 0);
        __syncthreads();
    }

    if (t < BM) rsum[t] = 0.f;
    __syncthreads();

#pragma unroll
    for (int m = 0; m < 2; ++m) {
#pragma unroll
        for (int i = 0; i < 4; ++i) {
            float val = 0.f;
#pragma unroll
            for (int n = 0; n < 4; ++n) {
                const int col = wc * 64 + 16 * n + lr;
                val += fmaxf(acc[m][n][i] + bias[col], 0.f) * w3[col];
            }
            val += __shfl_xor(val, 1);
            val += __shfl_xor(val, 2);
            val += __shfl_xor(val, 4);
            val += __shfl_xor(val, 8);
            if (lr == 0) atomicAdd(&rsum[16 * m + q * 4 + i], val);
        }
    }
    __syncthreads();
    if (t < BM)
        out[row0 + t] = 1.f / (1.f + expf(-(rsum[t] + b3[0])));
}

// ---------------------------------------------------------------------------
// Weight convert+transpose: dst[n][kp] = bf16(src[k][n]), zero-pad k>=K.
// ---------------------------------------------------------------------------
struct WConvArgs {
    const float* src[6];
    bf16*        dst[6];
    int K[6], N[6], Kp[6], t0[7];
};

__global__ __launch_bounds__(256) void wconv_kernel(WConvArgs a)
{
    __shared__ float Ts[32][33];
    int w = 0;
    while (w < 5 && (int)blockIdx.x >= a.t0[w + 1]) ++w;
    const int rel = blockIdx.x - a.t0[w];
    const int K = a.K[w], N = a.N[w], Kp = a.Kp[w];
    const int nbn = N >> 5;
    const int tk = rel / nbn, tn = rel % nbn;
    const int tx = threadIdx.x & 31, ty = threadIdx.x >> 5;

    const float* src = a.src[w];
    bf16* dst = a.dst[w];

#pragma unroll
    for (int rr = 0; rr < 4; ++rr) {
        const int k = tk * 32 + ty + rr * 8;
        const int n = tn * 32 + tx;
        Ts[ty + rr * 8][tx] = (k < K) ? src[(size_t)k * N + n] : 0.f;
    }
    __syncthreads();
#pragma unroll
    for (int rr = 0; rr < 4; ++rr) {
        const int n = tn * 32 + ty + rr * 8;
        const int kp = tk * 32 + tx;
        dst[(size_t)n * Kp + kp] = __float2bfloat16(Ts[tx][ty + rr * 8]);
    }
}

// ---------------------------------------------------------------------------
// Embedding gather + pairwise dots. One block per batch row (R3/R6-proven).
// bot (bf16) sits in R[b][0:64]; writes R[b][64+p], zero-pads [415,512).
// ---------------------------------------------------------------------------
__global__ __launch_bounds__(256) void interact_kernel(
    const int* __restrict__ cat_idx, const float* __restrict__ tables,
    bf16* __restrict__ R)
{
    __shared__ float T[NFEA][64 + 1];

    const int b    = blockIdx.x;
    const int t    = threadIdx.x;
    const int g    = t >> 6;
    const int lane = t & 63;
    bf16* Rrow = R + (size_t)b * RLD;

    for (int f = g; f < NFEA; f += 4) {
        if (f == 0) {
            T[0][lane] = __bfloat162float(Rrow[lane]);
        } else {
            const int j   = f - 1;
            const int idx = cat_idx[b * NSPARSE + j];
            T[f][lane] = tables[((size_t)j * VOCAB + idx) * 64 + lane];
        }
    }
    __syncthreads();

    if (t < RLD - 415) Rrow[415 + t] = __float2bfloat16(0.f);

    for (int p = t; p < NPAIR; p += 256) {
        int i = (int)((1.0f + sqrtf(1.0f + 8.0f * (float)p)) * 0.5f);
        while (i * (i - 1) / 2 > p) --i;
        while ((i + 1) * i / 2 <= p) ++i;
        const int j = p - i * (i - 1) / 2;
        float s = 0.f;
#pragma unroll 16
        for (int k = 0; k < 64; ++k) s += T[i][k] * T[j][k];
        Rrow[64 + p] = __float2bfloat16(s);
    }
}

// ---------------------------------------------------------------------------
extern "C" void kernel_launch(void* const* d_in, const int* in_sizes, int n_in,
                              void* d_out, int out_size, void* d_ws, size_t ws_size,
                              hipStream_t stream)
{
    const float* dense   = (const float*)d_in[0];
    const int*   cat_idx = (const int*)  d_in[1];
    const float* tables  = (const float*)d_in[2];
    const float* bw0 = (const float*)d_in[3];
    const float* bb0 = (const float*)d_in[4];
    const float* bw1 = (const float*)d_in[5];
    const float* bb1 = (const float*)d_in[6];
    const float* bw2 = (const float*)d_in[7];
    const float* bb2 = (const float*)d_in[8];
    const float* tw0 = (const float*)d_in[9];
    const float* tb0 = (const float*)d_in[10];
    const float* tw1 = (const float*)d_in[11];
    const float* tb1 = (const float*)d_in[12];
    const float* tw2 = (const float*)d_in[13];
    const float* tb2 = (const float*)d_in[14];
    const float* tw3 = (const float*)d_in[15];
    const float* tb3 = (const float*)d_in[16];

    bf16* p = (bf16*)d_ws;
    bf16* h0   = p; p += (size_t)BATCH * 512;
    bf16* h1   = p; p += (size_t)BATCH * 256;
    bf16* R    = p; p += (size_t)BATCH * RLD;
    bf16* r0   = p; p += (size_t)BATCH * 1024;
    bf16* r1   = p; p += (size_t)BATCH * 512;
    bf16* bw0t = p; p += 512 * 32;
    bf16* bw1t = p; p += 256 * 512;
    bf16* bw2t = p; p += 64 * 256;
    bf16* tw0t = p; p += 1024 * RLD;
    bf16* tw1t = p; p += 512 * 1024;
    bf16* tw2t = p; p += 256 * 512;
    float* out = (float*)d_out;

    WConvArgs wa;
    wa.src[0] = bw0;  wa.dst[0] = bw0t; wa.K[0] = 13;   wa.N[0] = 512;  wa.Kp[0] = 32;
    wa.src[1] = bw1;  wa.dst[1] = bw1t; wa.K[1] = 512;  wa.N[1] = 256;  wa.Kp[1] = 512;
    wa.src[2] = bw2;  wa.dst[2] = bw2t; wa.K[2] = 256;  wa.N[2] = 64;   wa.Kp[2] = 256;
    wa.src[3] = tw0;  wa.dst[3] = tw0t; wa.K[3] = 415;  wa.N[3] = 1024; wa.Kp[3] = RLD;
    wa.src[4] = tw1;  wa.dst[4] = tw1t; wa.K[4] = 1024; wa.N[4] = 512;  wa.Kp[4] = 1024;
    wa.src[5] = tw2;  wa.dst[5] = tw2t; wa.K[5] = 512;  wa.N[5] = 256;  wa.Kp[5] = 512;
    int tiles = 0;
    for (int w = 0; w < 6; ++w) {
        wa.t0[w] = tiles;
        tiles += (wa.Kp[w] >> 5) * (wa.N[w] >> 5);
    }
    wa.t0[6] = tiles;

    wconv_kernel<<<tiles, 256, 0, stream>>>(wa);

    // bottom MLP
    gemm_bf16<32, 2, 2, 2, 2, true ><<<(BATCH / 64) * (512 / 64), 256, 0, stream>>>(
        dense, bw0t, bb0, h0, BATCH, 512, 32, 512);
    // gemm1: BM=32 -> 256 blocks (was 128)
    gemm_bf16<128, 2, 2, 1, 2, false><<<(BATCH / 32) * (256 / 64), 256, 0, stream>>>(
        h0, bw1t, bb1, h1, BATCH, 256, 512, 256);
    // gemm2: BM=32 -> 64 blocks (was 32)
    gemm_bf16<128, 2, 2, 1, 2, false><<<(BATCH / 32) * (64 / 64), 256, 0, stream>>>(
        h1, bw2t, bb2, R, BATCH, 64, 256, RLD);   // bot -> R[:, :64]

    interact_kernel<<<BATCH, 256, 0, stream>>>(cat_idx, tables, R);

    // top MLP
    gemm_bf16<128, 2, 2, 2, 2, false><<<(BATCH / 64) * (1024 / 64), 256, 0, stream>>>(
        R, tw0t, tb0, r0, BATCH, 1024, RLD, 1024);
    // top1: BM=32 -> 512 blocks (was 256)
    gemm_bf16<128, 2, 2, 1, 2, false><<<(BATCH / 32) * (512 / 64), 256, 0, stream>>>(
        r0, tw1t, tb1, r1, BATCH, 512, 1024, 512);
    top2_kernel<<<BATCH / 32, 256, 0, stream>>>(r1, tw2t, tb2, tw3, tb3, out);
}